// Round 4
// baseline (242.969 us; speedup 1.0000x reference)
//
#include <hip/hip_runtime.h>
#include <hip/hip_bf16.h>
#include <math.h>

// Problem constants
#define NB 2
#define CC 256
#define NPOS 2304   // 48*48
#define NDELTA 95

typedef __attribute__((ext_vector_type(8))) short short8;
typedef __attribute__((ext_vector_type(4))) float floatx4;

__device__ inline unsigned short f2bf(float x) {
    unsigned int u = __float_as_uint(x);
    u = (u + 0x7FFFu + ((u >> 16) & 1u)) >> 16;
    return (unsigned short)u;
}
__device__ inline float bf2f(unsigned short h) {
    return __uint_as_float(((unsigned int)h) << 16);
}
__device__ inline unsigned int pk2(float a, float b) {
    return (unsigned int)f2bf(a) | ((unsigned int)f2bf(b) << 16);
}
// packed bf16 x bf16 -> bf16 multiply (v_pk_mul_bf16 on gfx950 if available)
__device__ inline unsigned int pkmul(unsigned int a, unsigned int b) {
    __hip_bfloat162 x = *(__hip_bfloat162*)&a;
    __hip_bfloat162 y = *(__hip_bfloat162*)&b;
    __hip_bfloat162 r = __hmul2(x, y);
    return *(unsigned int*)&r;
}

// ---------------------------------------------------------------------------
// Kernel 1: pos tables (posx/posy: [95][256]) + wk_eff ([8][256])
// ---------------------------------------------------------------------------
__global__ __launch_bounds__(256) void pos_tables_kernel(
    const float* __restrict__ Wx, const float* __restrict__ Wy,
    const float* __restrict__ Wk, const float* __restrict__ ab,
    float* __restrict__ posx, float* __restrict__ posy, float* __restrict__ wkeff)
{
    int b = blockIdx.x;
    int t = threadIdx.x;
    if (b < NDELTA) {
        __shared__ float emb[128];
        float delta = (float)(b - 47);
        if (t < 64) {
            float dim_inv = exp2f(-(float)t * 0.15571537944784511f); // log2(1000)/64
            float ang = 2.0f * delta * dim_inv;
            emb[t]      = sinf(ang);
            emb[t + 64] = cosf(ang);
        }
        __syncthreads();
        float sx = 0.f, sy = 0.f;
        const float* wxr = Wx + t * 128;
        const float* wyr = Wy + t * 128;
        for (int f = 0; f < 128; ++f) {
            float e = emb[f];
            sx += e * wxr[f];
            sy += e * wyr[f];
        }
        const float inv_sqrt2 = 0.70710678118654752440f;
        posx[b * 256 + t] = sx * inv_sqrt2;
        posy[b * 256 + t] = sy * inv_sqrt2;
    } else {
        int g = b - NDELTA;
        float s = 0.f;
        for (int d = 0; d < 32; ++d)
            s += ab[g * 32 + d] * Wk[(g * 32 + d) * 256 + t];
        wkeff[g * 256 + t] = s;
    }
}

// ---------------------------------------------------------------------------
// Kernel 2: fused Q/V/e_key projection GEMM.
// qbuf layout: [ng][p][32d]   vbuf layout: [n][256ch][p]   ek: [ng][p]
// ---------------------------------------------------------------------------
__global__ __launch_bounds__(256) void qkv_kernel(
    const float* __restrict__ x, const float* __restrict__ Wq,
    const float* __restrict__ Wv, const float* __restrict__ wkeff,
    float* __restrict__ qbuf, float* __restrict__ vbuf, float* __restrict__ ek)
{
    __shared__ float As[16][64];
    __shared__ float Bs[16][64];
    int mTile = blockIdx.x;   // 0..8
    int nTile = blockIdx.y;   // 0..71
    int t = threadIdx.x;
    int tx = t & 15, ty = t >> 4;
    int colBase = nTile * 64;
    int n = colBase / NPOS;
    int pBase = colBase - n * NPOS;

    int lo = t & 63;
    int lc = (t >> 6) * 4;
    int bc = t >> 4;
    int bp = (t & 15) * 4;

    float acc[4][4] = {};

    for (int k0 = 0; k0 < 256; k0 += 16) {
        int o = mTile * 64 + lo;
        float4 w4 = make_float4(0.f, 0.f, 0.f, 0.f);
        if (o < 256)      w4 = *(const float4*)(Wq + o * 256 + k0 + lc);
        else if (o < 512) w4 = *(const float4*)(Wv + (o - 256) * 256 + k0 + lc);
        else if (o < 520) w4 = *(const float4*)(wkeff + (o - 512) * 256 + k0 + lc);
        As[lc + 0][lo] = w4.x;
        As[lc + 1][lo] = w4.y;
        As[lc + 2][lo] = w4.z;
        As[lc + 3][lo] = w4.w;

        int c = k0 + bc;
        const float* xrowbase = x + (n * 256 + c) * (96 * 96);
        float bv[4];
        #pragma unroll
        for (int jj = 0; jj < 4; ++jj) {
            int p = pBase + bp + jj;
            int i = p / 48, j = p - i * 48;
            bv[jj] = xrowbase[(2 * i) * 96 + 2 * j];
        }
        *(float4*)&Bs[bc][bp] = make_float4(bv[0], bv[1], bv[2], bv[3]);
        __syncthreads();

        #pragma unroll
        for (int kk = 0; kk < 16; ++kk) {
            float4 av = *(const float4*)&As[kk][ty * 4];
            float4 b4 = *(const float4*)&Bs[kk][tx * 4];
            float a[4] = {av.x, av.y, av.z, av.w};
            float bb[4] = {b4.x, b4.y, b4.z, b4.w};
            #pragma unroll
            for (int i = 0; i < 4; ++i)
                #pragma unroll
                for (int j = 0; j < 4; ++j)
                    acc[i][j] += a[i] * bb[j];
        }
        __syncthreads();
    }

    #pragma unroll
    for (int i = 0; i < 4; ++i) {
        int o = mTile * 64 + ty * 4 + i;
        if (o >= 520) continue;
        int p0 = pBase + tx * 4;
        if (o < 256) {
            int g = o >> 5, d = o & 31;
            #pragma unroll
            for (int j = 0; j < 4; ++j)
                qbuf[((size_t)(n * 8 + g) * NPOS + p0 + j) * 32 + d] = acc[i][j];
        } else if (o < 512) {
            int o2 = o - 256;
            *(float4*)(vbuf + (size_t)(n * 256 + o2) * NPOS + p0) =
                make_float4(acc[i][0], acc[i][1], acc[i][2], acc[i][3]);
        } else {
            *(float4*)(ek + (size_t)(n * 8 + (o - 512)) * NPOS + p0) =
                make_float4(acc[i][0], acc[i][1], acc[i][2], acc[i][3]);
        }
    }
}

// ---------------------------------------------------------------------------
// Kernel 3: per-(n,g) A = exp(ek - max(ek)), in place.
// ---------------------------------------------------------------------------
__global__ __launch_bounds__(256) void softA_kernel(float* __restrict__ ekA)
{
    int ng = blockIdx.x;
    float* e = ekA + (size_t)ng * NPOS;
    int t = threadIdx.x;
    __shared__ float red[256];
    float m = -1e30f;
    for (int k = t; k < NPOS; k += 256) m = fmaxf(m, e[k]);
    red[t] = m;
    __syncthreads();
    for (int s = 128; s > 0; s >>= 1) {
        if (t < s) red[t] = fmaxf(red[t], red[t + s]);
        __syncthreads();
    }
    m = red[0];
    for (int k = t; k < NPOS; k += 256) e[k] = __expf(e[k] - m);
}

// ---------------------------------------------------------------------------
// Kernel 3b: V̂ = A*V in bf16 B-fragment order, once per (n,g).
// vhat layout: [ng][tile 0..23][576 uint4]; group grp=cc*3+nn, lane Ls:
//   nn<2: cols d=nn*16+(Ls&15), k-octet cc*32+((Ls>>4)<<3); nn==2: col0=A[k].
// ---------------------------------------------------------------------------
__global__ __launch_bounds__(256) void vhat_kernel(
    const float* __restrict__ vbuf, const float* __restrict__ ekA,
    uint4* __restrict__ vhat)
{
    int tile = blockIdx.x;   // 0..23
    int ng = blockIdx.y;     // 0..15
    int k0 = tile * 96;
    int t = threadIdx.x;
    const float* vb = vbuf + (size_t)ng * 32 * NPOS;   // [32 d][2304 k]
    const float* Ab = ekA + (size_t)ng * NPOS;
    uint4* out = vhat + ((size_t)ng * 24 + tile) * 576;

    for (int s = t; s < 576; s += 256) {
        int grp = s >> 6;
        int Ls = s & 63;
        int cc = grp / 3;
        int nn = grp - cc * 3;
        int koct = cc * 32 + ((Ls >> 4) << 3);
        uint4 w = make_uint4(0u, 0u, 0u, 0u);
        if (nn < 2) {
            int d = nn * 16 + (Ls & 15);
            const float* vp = vb + (size_t)d * NPOS + k0 + koct;
            const float* ap = Ab + k0 + koct;
            float4 v0 = *(const float4*)vp;
            float4 v1 = *(const float4*)(vp + 4);
            float4 a0 = *(const float4*)ap;
            float4 a1 = *(const float4*)(ap + 4);
            w.x = pk2(v0.x * a0.x, v0.y * a0.y);
            w.y = pk2(v0.z * a0.z, v0.w * a0.w);
            w.z = pk2(v1.x * a1.x, v1.y * a1.y);
            w.w = pk2(v1.z * a1.z, v1.w * a1.w);
        } else if ((Ls & 15) == 0) {
            const float* ap = Ab + k0 + koct;
            float4 a0 = *(const float4*)ap;
            float4 a1 = *(const float4*)(ap + 4);
            w.x = pk2(a0.x, a0.y);
            w.y = pk2(a0.z, a0.w);
            w.z = pk2(a1.x, a1.y);
            w.w = pk2(a1.z, a1.w);
        }
        out[s] = w;
    }
}

// ---------------------------------------------------------------------------
// Kernel 4: attention via bf16 MFMA, double-buffered V̂ tiles.
// Block = 256 thr (4 waves), Q-tile 64, k-tile 96. One barrier per tile.
// A-fragment (P = X*Y) built in registers (packed bf16 mul).
// ---------------------------------------------------------------------------
__global__ __launch_bounds__(256) void attn_kernel(
    const float* __restrict__ qbuf, const uint4* __restrict__ vhat,
    const float* __restrict__ posx, const float* __restrict__ posy,
    float* __restrict__ oattn)
{
    __shared__ __align__(16) unsigned short Vbuf[2][576 * 8];  // 2 x 9216 B
    __shared__ unsigned short Xs[64 * 50];                     // 6400 B
    __shared__ unsigned short Ys[64 * 50];                     // 6400 B
    __shared__ float linv_s[64];

    int blk = blockIdx.x;
    int qt = blk % 36;
    int ng = blk / 36;
    int nb = ng >> 3, g = ng & 7;
    int qbase = qt * 64;
    int t = threadIdx.x;
    int m = t >> 6;     // wave id = q-group
    int L = t & 63;

    // ---- e_x / e_y phase: X = exp(q·posx), Y = exp(q·posy) (no shift) ----
    {
        int qlo = L >> 3, rlo = L & 7;
        for (int pass = 0; pass < 2; ++pass) {
            int oct = pass * 4 + m;           // q-octet 0..7
            int q = oct * 8 + qlo;
            int qglob = qbase + q;
            int base8 = qbase + oct * 8;
            int hq0 = base8 / 48;
            int sq0 = base8 - hq0 * 48;       // no wrap within octet
            int wq = sq0 + qlo;
            float Qr[32];
            const float* qsrc = qbuf + ((size_t)ng * NPOS + qglob) * 32;
            #pragma unroll
            for (int j = 0; j < 8; ++j) {
                float4 qv = *(const float4*)(qsrc + j * 4);
                Qr[j * 4 + 0] = qv.x; Qr[j * 4 + 1] = qv.y;
                Qr[j * 4 + 2] = qv.z; Qr[j * 4 + 3] = qv.w;
            }
            #pragma unroll
            for (int rb = 0; rb < 7; ++rb) {
                int row = sq0 + rb * 8 + rlo;
                if (row < 95) {
                    const float* px = posx + (size_t)row * 256 + g * 32;
                    float s = 0.f;
                    #pragma unroll
                    for (int ch = 0; ch < 8; ++ch) {
                        float4 pv = *(const float4*)(px + ch * 4);
                        s += pv.x * Qr[ch*4+0] + pv.y * Qr[ch*4+1]
                           + pv.z * Qr[ch*4+2] + pv.w * Qr[ch*4+3];
                    }
                    int v = wq - row + 47;
                    if (v >= 0 && v < 48)
                        Xs[q * 50 + v] = f2bf(__expf(s));
                }
            }
            #pragma unroll
            for (int rb = 0; rb < 7; ++rb) {
                int row = hq0 + rb * 8 + rlo;
                if (row < 95) {
                    const float* py = posy + (size_t)row * 256 + g * 32;
                    float s = 0.f;
                    #pragma unroll
                    for (int ch = 0; ch < 8; ++ch) {
                        float4 pv = *(const float4*)(py + ch * 4);
                        s += pv.x * Qr[ch*4+0] + pv.y * Qr[ch*4+1]
                           + pv.z * Qr[ch*4+2] + pv.w * Qr[ch*4+3];
                    }
                    int u = hq0 - row + 47;
                    if (u >= 0 && u < 48)
                        Ys[q * 50 + u] = f2bf(__expf(s));
                }
            }
        }
    }
    __syncthreads();

    // ---- preload packed X pairs: Xp[c*4+jj] = (X[k], X[k+1]) bf16x2 ----
    int qp = m * 16 + (L & 15);
    int o = L >> 4;
    unsigned int Xp[12];
    #pragma unroll
    for (int c = 0; c < 3; ++c)
        #pragma unroll
        for (int jj = 0; jj < 4; ++jj) {
            int k = c * 32 + o * 8 + jj * 2;       // even; pair never straddles 48
            int v0 = (k < 48) ? k : k - 48;
            int v1 = v0 + 1;
            Xp[c * 4 + jj] = (unsigned int)Xs[qp * 50 + v0]
                           | ((unsigned int)Xs[qp * 50 + v1] << 16);
        }

    const uint4* vb = vhat + (size_t)ng * 24 * 576;

    // ---- prologue: stage tile 0 into Vbuf[0] ----
    {
        uint4* dst = (uint4*)Vbuf[0];
        dst[t] = vb[t];
        dst[t + 256] = vb[t + 256];
        if (t < 64) dst[t + 512] = vb[t + 512];
    }

    floatx4 acc0 = {0.f, 0.f, 0.f, 0.f};
    floatx4 acc1 = {0.f, 0.f, 0.f, 0.f};
    floatx4 acc2 = {0.f, 0.f, 0.f, 0.f};

    for (int tile = 0; tile < 24; ++tile) {
        int cur = tile & 1;
        __syncthreads();   // Vbuf[cur] visible; prior reads of Vbuf[cur^1] done

        // register prefetch of next tile (overlaps with MFMA below)
        uint4 p0, p1, p2;
        if (tile + 1 < 24) {
            const uint4* src = vb + (tile + 1) * 576;
            p0 = src[t];
            p1 = src[t + 256];
            if (t < 64) p2 = src[t + 512];
        }

        // Y broadcast packs for this tile's two u-rows
        int u0 = tile * 2;
        unsigned int y0 = Ys[qp * 50 + u0];     y0 |= y0 << 16;
        unsigned int y1 = Ys[qp * 50 + u0 + 1]; y1 |= y1 << 16;
        unsigned int Yc[3];
        Yc[0] = y0; Yc[1] = (o < 2) ? y0 : y1; Yc[2] = y1;

        const unsigned short* VB = Vbuf[cur];
        #pragma unroll
        for (int c = 0; c < 3; ++c) {
            unsigned int yv = Yc[c];
            union { unsigned int u[4]; short8 s; } av;
            av.u[0] = pkmul(Xp[c * 4 + 0], yv);
            av.u[1] = pkmul(Xp[c * 4 + 1], yv);
            av.u[2] = pkmul(Xp[c * 4 + 2], yv);
            av.u[3] = pkmul(Xp[c * 4 + 3], yv);
            short8 a = av.s;
            short8 b0 = *(const short8*)&VB[((c * 3 + 0) * 64 + L) * 8];
            short8 b1 = *(const short8*)&VB[((c * 3 + 1) * 64 + L) * 8];
            short8 b2 = *(const short8*)&VB[((c * 3 + 2) * 64 + L) * 8];
            acc0 = __builtin_amdgcn_mfma_f32_16x16x32_bf16(a, b0, acc0, 0, 0, 0);
            acc1 = __builtin_amdgcn_mfma_f32_16x16x32_bf16(a, b1, acc1, 0, 0, 0);
            acc2 = __builtin_amdgcn_mfma_f32_16x16x32_bf16(a, b2, acc2, 0, 0, 0);
        }

        // write prefetched tile into the other buffer
        if (tile + 1 < 24) {
            uint4* dst = (uint4*)Vbuf[cur ^ 1];
            dst[t] = p0;
            dst[t + 256] = p1;
            if (t < 64) dst[t + 512] = p2;
        }
    }

    // ---- epilogue: l from acc2 col 0, normalize, store ----
    if ((L & 15) == 0) {
        int qc = m * 16 + (L >> 4) * 4;
        #pragma unroll
        for (int r = 0; r < 4; ++r)
            linv_s[qc + r] = 1.0f / acc2[r];
    }
    __syncthreads();
    {
        int qc = m * 16 + (L >> 4) * 4;
        float4 li = *(const float4*)&linv_s[qc];
        int d0 = L & 15;
        float* r0 = oattn + ((size_t)(nb * 256 + g * 32 + d0)) * NPOS + qbase + qc;
        *(float4*)r0 = make_float4(acc0[0] * li.x, acc0[1] * li.y,
                                   acc0[2] * li.z, acc0[3] * li.w);
        float* r1 = oattn + ((size_t)(nb * 256 + g * 32 + 16 + d0)) * NPOS + qbase + qc;
        *(float4*)r1 = make_float4(acc1[0] * li.x, acc1[1] * li.y,
                                   acc1[2] * li.z, acc1[3] * li.w);
    }
}

// ---------------------------------------------------------------------------
// Kernel 5: output projection GEMM
// ---------------------------------------------------------------------------
__global__ __launch_bounds__(256) void proj_kernel(
    const float* __restrict__ oattn, const float* __restrict__ Wp,
    const float* __restrict__ bpv, float* __restrict__ proj)
{
    __shared__ float As[16][64];
    __shared__ float Bs[16][64];
    int mTile = blockIdx.x;   // 0..3
    int nTile = blockIdx.y;   // 0..71
    int t = threadIdx.x;
    int tx = t & 15, ty = t >> 4;
    int colBase = nTile * 64;
    int n = colBase / NPOS;
    int pBase = colBase - n * NPOS;

    int lo = t & 63;
    int lc = (t >> 6) * 4;
    int bc = t >> 4;
    int bp = (t & 15) * 4;

    float acc[4][4] = {};

    for (int k0 = 0; k0 < 256; k0 += 16) {
        int o = mTile * 64 + lo;
        float4 w4 = *(const float4*)(Wp + o * 256 + k0 + lc);
        As[lc + 0][lo] = w4.x;
        As[lc + 1][lo] = w4.y;
        As[lc + 2][lo] = w4.z;
        As[lc + 3][lo] = w4.w;
        int c = k0 + bc;
        *(float4*)&Bs[bc][bp] =
            *(const float4*)(oattn + ((size_t)(n * 256 + c)) * NPOS + pBase + bp);
        __syncthreads();
        #pragma unroll
        for (int kk = 0; kk < 16; ++kk) {
            float4 av = *(const float4*)&As[kk][ty * 4];
            float4 b4 = *(const float4*)&Bs[kk][tx * 4];
            float a[4] = {av.x, av.y, av.z, av.w};
            float bb[4] = {b4.x, b4.y, b4.z, b4.w};
            #pragma unroll
            for (int i = 0; i < 4; ++i)
                #pragma unroll
                for (int j = 0; j < 4; ++j)
                    acc[i][j] += a[i] * bb[j];
        }
        __syncthreads();
    }

    #pragma unroll
    for (int i = 0; i < 4; ++i) {
        int o = mTile * 64 + ty * 4 + i;
        float bias = bpv[o];
        *(float4*)(proj + ((size_t)(n * 256 + o)) * NPOS + pBase + tx * 4) =
            make_float4(acc[i][0] + bias, acc[i][1] + bias,
                        acc[i][2] + bias, acc[i][3] + bias);
    }
}

// ---------------------------------------------------------------------------
// Kernel 6: bilinear 48->96 upsample + residual
// ---------------------------------------------------------------------------
__global__ __launch_bounds__(256) void resize_kernel(
    const float* __restrict__ proj, const float* __restrict__ x,
    const float* __restrict__ gamma, float* __restrict__ out)
{
    int idx = blockIdx.x * 256 + threadIdx.x;
    int J = idx % 96;
    int tmp = idx / 96;
    int I = tmp % 96;
    int nc = tmp / 96;

    int jr = I >> 1;
    int r0, r1; float w0, w1;
    if ((I & 1) == 0) { r0 = (jr > 0) ? jr - 1 : 0; r1 = jr; w0 = 0.25f; w1 = 0.75f; }
    else              { r0 = jr; r1 = (jr < 47) ? jr + 1 : 47; w0 = 0.75f; w1 = 0.25f; }
    int jc = J >> 1;
    int c0, c1; float u0, u1;
    if ((J & 1) == 0) { c0 = (jc > 0) ? jc - 1 : 0; c1 = jc; u0 = 0.25f; u1 = 0.75f; }
    else              { c0 = jc; c1 = (jc < 47) ? jc + 1 : 47; u0 = 0.75f; u1 = 0.25f; }

    const float* P = proj + (size_t)nc * NPOS;
    float v = w0 * (u0 * P[r0 * 48 + c0] + u1 * P[r0 * 48 + c1]) +
              w1 * (u0 * P[r1 * 48 + c0] + u1 * P[r1 * 48 + c1]);
    out[idx] = gamma[0] * v + x[idx];
}

// ---------------------------------------------------------------------------
extern "C" void kernel_launch(void* const* d_in, const int* in_sizes, int n_in,
                              void* d_out, int out_size, void* d_ws, size_t ws_size,
                              hipStream_t stream)
{
    const float* x     = (const float*)d_in[0];
    const float* Wq    = (const float*)d_in[1];
    const float* Wk    = (const float*)d_in[2];
    const float* Wv    = (const float*)d_in[3];
    const float* Wx    = (const float*)d_in[4];
    const float* Wy    = (const float*)d_in[5];
    const float* ab    = (const float*)d_in[6];
    const float* Wp    = (const float*)d_in[7];
    const float* bp    = (const float*)d_in[8];
    const float* gamma = (const float*)d_in[9];
    float* out = (float*)d_out;

    float* ws = (float*)d_ws;
    float* posx  = ws;                               // 95*256
    float* posy  = posx + 95 * 256;                  // 95*256
    float* wkeff = posy + 95 * 256;                  // 8*256
    float* qbuf  = wkeff + 8 * 256;                  // 2*8*2304*32  [ng][p][32]
    float* vbuf  = qbuf + 2 * 8 * NPOS * 32;         // 2*8*2304*32  [n][256][p]
    float* ekA   = vbuf + 2 * 8 * NPOS * 32;         // 2*8*2304
    float* oattn = ekA + 2 * 8 * NPOS;               // 2*256*2304
    float* proj  = oattn + 2 * 256 * NPOS;           // 2*256*2304
    // vhat (3.54 MB) aliases proj (4.72 MB): vhat is dead before proj_kernel writes.
    uint4* vhat  = (uint4*)proj;                     // 16*24*576 uint4

    hipLaunchKernelGGL(pos_tables_kernel, dim3(103), dim3(256), 0, stream,
                       Wx, Wy, Wk, ab, posx, posy, wkeff);
    hipLaunchKernelGGL(qkv_kernel, dim3(9, 72), dim3(256), 0, stream,
                       x, Wq, Wv, wkeff, qbuf, vbuf, ekA);
    hipLaunchKernelGGL(softA_kernel, dim3(16), dim3(256), 0, stream, ekA);
    hipLaunchKernelGGL(vhat_kernel, dim3(24, 16), dim3(256), 0, stream,
                       vbuf, ekA, vhat);
    hipLaunchKernelGGL(attn_kernel, dim3(576), dim3(256), 0, stream,
                       qbuf, vhat, posx, posy, oattn);
    hipLaunchKernelGGL(proj_kernel, dim3(4, 72), dim3(256), 0, stream,
                       oattn, Wp, bp, proj);
    hipLaunchKernelGGL(resize_kernel, dim3((2 * 256 * 96 * 96) / 256), dim3(256), 0, stream,
                       proj, x, gamma, out);
}